// Round 5
// baseline (312.738 us; speedup 1.0000x reference)
//
#include <hip/hip_runtime.h>
#include <cfloat>

#define B_ 32
#define N_ 4096
#define C_ 768
#define T_ 1000
#define K_ 20

#define PXB 256           // pixels per k2 block
#define PHC 16            // floats per c-phase (64 B per px per phase)
#define NPH (C_/PHC)      // 48 phases
#define GAP_TH 1e-3f
#define MAXF 16384

typedef float f32x4 __attribute__((ext_vector_type(4)));

// ---------------- K1a: vg_logit in fp64 (+ zero counters) ----------------
__global__ __launch_bounds__(256) void k1_logits(const float* __restrict__ g_feat,
                                                 const float* __restrict__ text,
                                                 double* __restrict__ logits,
                                                 int* __restrict__ cnt,
                                                 int* __restrict__ flagcnt) {
    int b = blockIdx.x;
    int wid = threadIdx.x >> 6, lane = threadIdx.x & 63;
    int t = blockIdx.y * 4 + wid;           // grid.y = 250 -> t in [0,1000)
    if (b == 0 && blockIdx.y == 0) {
        for (int i = threadIdx.x; i < B_ * K_; i += 256) cnt[i] = 0;
        if (threadIdx.x == 0) flagcnt[0] = 0;
    }
    const float* g = g_feat + b * C_;
    const float* e = text + t * C_;
    double s = 0.0;
    #pragma unroll
    for (int j = 0; j < 12; ++j) {
        int c = lane + 64 * j;
        s += (double)g[c] * (double)e[c];
    }
    #pragma unroll
    for (int m = 32; m; m >>= 1) s += __shfl_xor(s, m);
    if (lane == 0) logits[b * T_ + t] = s;
}

// ---------------- K1b: top-20 per batch (1-wave shuffle select) + gather ----------------
__global__ __launch_bounds__(256) void k1b_topk(const double* __restrict__ logits,
                                                const float* __restrict__ text,
                                                float* __restrict__ agg,
                                                int* __restrict__ sel) {
    __shared__ int ssel[K_];
    int b = blockIdx.x, tid = threadIdx.x, lane = tid & 63;
    if (tid < 64) {
        double v[16];
        #pragma unroll
        for (int j = 0; j < 16; ++j) {
            int t = lane + 64 * j;
            v[j] = (t < T_) ? logits[b * T_ + t] : -DBL_MAX;
        }
        for (int it = 0; it < K_; ++it) {
            double bv = -DBL_MAX; int bi = 0x7fffffff;
            #pragma unroll
            for (int j = 0; j < 16; ++j) {
                int t = lane + 64 * j;
                if (v[j] > bv) { bv = v[j]; bi = t; }
            }
            #pragma unroll
            for (int m = 32; m; m >>= 1) {
                double ov = __shfl_xor(bv, m); int oi = __shfl_xor(bi, m);
                if (ov > bv || (ov == bv && oi < bi)) { bv = ov; bi = oi; }
            }
            if (lane == 0) ssel[it] = bi;
            #pragma unroll
            for (int j = 0; j < 16; ++j) {
                int t = lane + 64 * j;
                if (t == bi) v[j] = -DBL_MAX;
            }
        }
    }
    __syncthreads();
    if (tid < K_) sel[b * K_ + tid] = ssel[tid];
    for (int i = tid; i < K_ * C_; i += 256) {
        int j = i / C_, c = i - j * C_;
        agg[b * K_ * C_ + i] = text[ssel[j] * C_ + c];
    }
}

// ---------------- K2: per-pixel argmax, 2 px/thread, 3-deep pipelined staging ----------------
// 128 threads = 2 waves; 256 px/block; per phase per wave: 8 f-loads + 1 e-load
// via global_load_lds; quad buffer; counted s_waitcnt vmcnt(27) keeps 3 stages
// in flight across raw s_barriers. f chunks stored at phys = c ^ ((c>>3)&7).
__global__ __launch_bounds__(128) void k2_argmax(const float* __restrict__ feat,
                                                 const float* __restrict__ agg,
                                                 int* __restrict__ kidx,
                                                 int* __restrict__ cnt,
                                                 int* __restrict__ flagcnt,
                                                 int* __restrict__ flaglist) {
    __shared__ float fbuf[4][PXB * PHC];      // 4 x 16 KB
    __shared__ float ebuf[4][512];            // 4 x 2 KB
    __shared__ int scnt[K_];
    int bx = blockIdx.x;
    int b = bx >> 4, tile = bx & 15;
    int n0 = tile * PXB;
    int tid = threadIdx.x, wid = tid >> 6, lane = tid & 63;
    if (tid < K_) scnt[tid] = 0;
    __syncthreads();

    const float* fb = feat + ((size_t)b * N_ + n0) * C_;
    const float* eb = agg + b * (K_ * C_);

    int se = wid * 64 + lane;
    int ce = se < 80 ? se : 79;
    const float* esrc = eb + (ce >> 2) * C_ + (ce & 3) * 4;

    auto stage = [&](int p, int bufi) {
        #pragma unroll
        for (int ii = 0; ii < 8; ++ii) {
            int s = (wid * 8 + ii) * 64 + lane;       // phys 16B slot
            int c = s ^ ((s >> 3) & 7);               // logical chunk
            int px = c >> 2, j = c & 3;
            const float* g = fb + (size_t)px * C_ + p * PHC + j * 4;
            float* d = &fbuf[bufi][(wid * 8 + ii) * 256];  // wave-uniform; HW adds lane*16
            __builtin_amdgcn_global_load_lds((const __attribute__((address_space(1))) void*)g,
                                             (__attribute__((address_space(3))) void*)d, 16, 0, 0);
        }
        {
            const float* g = esrc + p * PHC;
            float* d = &ebuf[bufi][wid * 256];
            __builtin_amdgcn_global_load_lds((const __attribute__((address_space(1))) void*)g,
                                             (__attribute__((address_space(3))) void*)d, 16, 0, 0);
        }
    };

    float acc0[K_], acc1[K_];
    #pragma unroll
    for (int k = 0; k < K_; ++k) { acc0[k] = 0.f; acc1[k] = 0.f; }

    stage(0, 0);
    stage(1, 1);
    stage(2, 2);

    int p0 = tid, p1 = tid + 128;                     // this thread's two pixels
    #pragma unroll 1
    for (int p = 0; p < NPH; ++p) {
        int bufi = p & 3;
        if (p + 3 < NPH) {
            stage(p + 3, (p + 3) & 3);
            asm volatile("s_waitcnt vmcnt(27)" ::: "memory");   // phase p's 9 landed
        } else if (p + 2 < NPH) {
            asm volatile("s_waitcnt vmcnt(18)" ::: "memory");
        } else if (p + 1 < NPH) {
            asm volatile("s_waitcnt vmcnt(9)" ::: "memory");
        } else {
            asm volatile("s_waitcnt vmcnt(0)" ::: "memory");
        }
        asm volatile("s_barrier" ::: "memory");

        const float* fB = fbuf[bufi];
        const float* eB = ebuf[bufi];
        f32x4 F0[4], F1[4];
        #pragma unroll
        for (int j = 0; j < 4; ++j) {
            int c0 = p0 * 4 + j, h0 = c0 ^ ((c0 >> 3) & 7);
            F0[j] = *(const f32x4*)(fB + h0 * 4);
            int c1 = p1 * 4 + j, h1 = c1 ^ ((c1 >> 3) & 7);
            F1[j] = *(const f32x4*)(fB + h1 * 4);
        }
        #pragma unroll
        for (int k = 0; k < K_; ++k) {
            float a0 = acc0[k], a1 = acc1[k];
            #pragma unroll
            for (int j = 0; j < 4; ++j) {
                f32x4 e = *(const f32x4*)(eB + (k * 4 + j) * 4);  // broadcast
                a0 = fmaf(F0[j].x, e.x, a0); a0 = fmaf(F0[j].y, e.y, a0);
                a0 = fmaf(F0[j].z, e.z, a0); a0 = fmaf(F0[j].w, e.w, a0);
                a1 = fmaf(F1[j].x, e.x, a1); a1 = fmaf(F1[j].y, e.y, a1);
                a1 = fmaf(F1[j].z, e.z, a1); a1 = fmaf(F1[j].w, e.w, a1);
            }
            acc0[k] = a0; acc1[k] = a1;
        }
        asm volatile("s_barrier" ::: "memory");       // buf reuse protection
    }

    // epilogue: top-2 scan for both pixels (first-max-wins == jnp.argmax)
    #pragma unroll
    for (int q = 0; q < 2; ++q) {
        float* acc = q ? acc1 : acc0;
        float m1 = acc[0]; int i1 = 0; float m2 = -FLT_MAX;
        #pragma unroll
        for (int k = 1; k < K_; ++k) {
            float v = acc[k];
            if (v > m1) { m2 = m1; m1 = v; i1 = k; }
            else if (v > m2) m2 = v;
        }
        int n = n0 + tid + q * 128;
        kidx[b * N_ + n] = i1;
        atomicAdd(&scnt[i1], 1);
        if (m1 - m2 < GAP_TH) {
            int pos = atomicAdd(flagcnt, 1);
            if (pos < MAXF) flaglist[pos] = b * N_ + n;
        }
    }
    __syncthreads();
    if (tid < K_) atomicAdd(&cnt[b * K_ + tid], scnt[tid]);
}

// ---------------- K2.5: fp64 re-decision for knife-edge pixels ----------------
__global__ __launch_bounds__(256) void k25_refine(const float* __restrict__ feat,
                                                  const float* __restrict__ agg,
                                                  int* __restrict__ kidx,
                                                  int* __restrict__ cnt,
                                                  const int* __restrict__ flagcnt,
                                                  const int* __restrict__ flaglist) {
    int wid = threadIdx.x >> 6, lane = threadIdx.x & 63;
    int wg = blockIdx.x * 4 + wid;
    int nf = flagcnt[0]; if (nf > MAXF) nf = MAXF;
    for (int e = wg; e < nf; e += gridDim.x * 4) {
        int pix = flaglist[e];
        int b = pix >> 12;
        const float* fr = feat + (size_t)pix * C_;
        const float* ebase = agg + b * K_ * C_;
        double fd[12];
        #pragma unroll
        for (int j = 0; j < 12; ++j) fd[j] = (double)fr[lane + 64 * j];
        double best = -DBL_MAX; int bi = 0;
        for (int k = 0; k < K_; ++k) {
            const float* er = ebase + k * C_;
            double s = 0.0;
            #pragma unroll
            for (int j = 0; j < 12; ++j) s += fd[j] * (double)er[lane + 64 * j];
            #pragma unroll
            for (int m = 32; m; m >>= 1) s += __shfl_xor(s, m);
            if (s > best) { best = s; bi = k; }
        }
        if (lane == 0) {
            int old = kidx[pix];
            if (old != bi) {
                kidx[pix] = bi;
                atomicSub(&cnt[b * K_ + old], 1);
                atomicAdd(&cnt[b * K_ + bi], 1);
            }
        }
    }
}

// ---------------- K4: broadcast-write output (8 px/wave, plain stores) ----------------
__global__ __launch_bounds__(256) void k4_out(const float* __restrict__ agg,
                                              const int* __restrict__ cnt,
                                              const int* __restrict__ kidx,
                                              float* __restrict__ out) {
    int wid = threadIdx.x >> 6, lane = threadIdx.x & 63;
    int wg = blockIdx.x * 4 + wid;          // 16384 waves, 8 px each
    int base = wg * 8;
    int b = base >> 12;                     // wave-uniform (8 | 4096)
    int kk[8];
    #pragma unroll
    for (int i = 0; i < 8; ++i) kk[i] = kidx[base + i];
    float sc[8];
    #pragma unroll
    for (int i = 0; i < 8; ++i) sc[i] = 1.0f / ((float)cnt[b * K_ + kk[i]] + 1.0f);
    const f32x4* agg4 = (const f32x4*)agg;
    f32x4* out4 = (f32x4*)out;
    #pragma unroll
    for (int i = 0; i < 8; ++i) {
        const f32x4* a4 = agg4 + (size_t)(b * K_ + kk[i]) * (C_ / 4);
        f32x4* o4 = out4 + (size_t)(base + i) * (C_ / 4);
        #pragma unroll
        for (int j = 0; j < 3; ++j) {
            f32x4 v = a4[lane + 64 * j];
            v *= sc[i];
            o4[lane + 64 * j] = v;          // plain store: through-L2 write stream
        }
    }
}

extern "C" void kernel_launch(void* const* d_in, const int* in_sizes, int n_in,
                              void* d_out, int out_size, void* d_ws, size_t ws_size,
                              hipStream_t stream) {
    const float* g_feat = (const float*)d_in[0];
    const float* feat   = (const float*)d_in[1];
    // d_in[2] = tau: positive scale, numerically irrelevant (attn == y_hard exactly)
    const float* text   = (const float*)d_in[3];
    float* out = (float*)d_out;

    char* ws = (char*)d_ws;
    double* logits = (double*)(ws + 0);              // 256000 B
    float*  agg    = (float*) (ws + 262144);         // 1966080 B
    int*    sel    = (int*)   (ws + 2228224);        // 2560 B
    int*    cnt    = (int*)   (ws + 2230784);        // 2560 B
    int*    flagc  = (int*)   (ws + 2233344);        // 64 B
    int*    flagl  = (int*)   (ws + 2233408);        // 65536 B
    int*    kidx   = (int*)   (ws + 2301504);        // 524288 B

    k1_logits<<<dim3(32, 250), 256, 0, stream>>>(g_feat, text, logits, cnt, flagc);
    k1b_topk<<<32, 256, 0, stream>>>(logits, text, agg, sel);
    k2_argmax<<<32 * 16, 128, 0, stream>>>(feat, agg, kidx, cnt, flagc, flagl);
    k25_refine<<<64, 256, 0, stream>>>(feat, agg, kidx, cnt, flagc, flagl);
    k4_out<<<4096, 256, 0, stream>>>(agg, cnt, kidx, out);
}